// Round 7
// baseline (129264.673 us; speedup 1.0000x reference)
//
#include <hip/hip_runtime.h>
#include <cstdint>

#define TT 256
#define HH 256
#define LL 3
#define NTH 1024
#define LN_EPS 1e-5f

// ---------------- helpers ----------------

__device__ __forceinline__ float fast_sigmoid(float x) {
    return 1.f / (1.f + __expf(-x));
}
__device__ __forceinline__ float fast_tanh(float x) {
    float xc = fminf(fmaxf(x, -15.f), 15.f);
    float e = __expf(2.f * xc);
    return 1.f - 2.f / (e + 1.f);
}
__device__ __forceinline__ float relu(float x) { return fmaxf(x, 0.f); }

// Per-row dual reduction. Threads are (n = tid&255, r = tid>>8); each row r
// occupies waves 4r..4r+3. Sums a,b over the 256 threads of each row.
__device__ __forceinline__ float2 red2row(float a, float b, float* scr, int tid) {
#pragma unroll
    for (int o = 32; o > 0; o >>= 1) {
        a += __shfl_down(a, o);
        b += __shfl_down(b, o);
    }
    int w = (tid >> 6) & 3;
    int r = tid >> 8;
    if ((tid & 63) == 0) { scr[r * 8 + w] = a; scr[r * 8 + 4 + w] = b; }
    __syncthreads();
    float s = 0.f, s2 = 0.f;
#pragma unroll
    for (int i = 0; i < 4; i++) { s += scr[r * 8 + i]; s2 += scr[r * 8 + 4 + i]; }
    return make_float2(s, s2);
}

// Head dual reduction: threads t<512 are (m = t&127, r = t>>7); each row = 2
// waves. Threads >=512 must pass a=b=0 (their wave leaders don't write).
__device__ __forceinline__ float2 red2head(float a, float b, float* scr, int tid) {
#pragma unroll
    for (int o = 32; o > 0; o >>= 1) {
        a += __shfl_down(a, o);
        b += __shfl_down(b, o);
    }
    int w = tid >> 6;
    if ((tid & 63) == 0 && w < 8) { scr[w] = a; scr[16 + w] = b; }
    __syncthreads();
    int r = (tid >> 7) & 3;
    return make_float2(scr[2 * r] + scr[2 * r + 1], scr[16 + 2 * r] + scr[16 + 2 * r + 1]);
}

__device__ __forceinline__ void fma16(float4 w, float4 x,
                                      float4& a0, float4& a1, float4& a2, float4& a3) {
    a0.x = fmaf(w.x, x.x, a0.x); a0.y = fmaf(w.y, x.x, a0.y);
    a0.z = fmaf(w.z, x.x, a0.z); a0.w = fmaf(w.w, x.x, a0.w);
    a1.x = fmaf(w.x, x.y, a1.x); a1.y = fmaf(w.y, x.y, a1.y);
    a1.z = fmaf(w.z, x.y, a1.z); a1.w = fmaf(w.w, x.y, a1.w);
    a2.x = fmaf(w.x, x.z, a2.x); a2.y = fmaf(w.y, x.z, a2.y);
    a2.z = fmaf(w.z, x.z, a2.z); a2.w = fmaf(w.w, x.z, a2.w);
    a3.x = fmaf(w.x, x.w, a3.x); a3.y = fmaf(w.y, x.w, a3.y);
    a3.z = fmaf(w.z, x.w, a3.z); a3.w = fmaf(w.w, x.w, a3.w);
}

// 4-row matvec: dst[(g*4+r)*N + n] = sum_{k in group g} xT[k][r] * W[k][n].
// W fp32 row-major [K,N] read as float4 (one 16B load feeds 16 FMAs).
// xT is LDS [K][4]. nQ*G must equal 1024 (all threads busy).
// K-loop is software-pipelined with two float4[4] register buffers (32 VGPRs)
// -> steady-state ~8 global loads in flight per lane. Needs the 128-VGPR
// budget from __launch_bounds__(1024, 1) (1 block/CU).
template <int K, int N, int G>
__device__ __forceinline__ void matvecR(const float* __restrict__ Wp,
                                        const float* __restrict__ xT,
                                        float* __restrict__ dst, int t) {
    constexpr int nQ = N / 4;
    constexpr int kc = K / G;
    static_assert(nQ * G == NTH, "bad split");
    int g = t / nQ;
    int j = t - g * nQ;
    const float4* Wq = (const float4*)Wp + (size_t)(g * kc) * nQ + j;
    const float4* xq = (const float4*)xT + g * kc;
    float4 a0 = {0,0,0,0}, a1 = {0,0,0,0}, a2 = {0,0,0,0}, a3 = {0,0,0,0};

    if constexpr ((kc % 8) == 0) {
        float4 b0[4], b1[4];
#pragma unroll
        for (int i = 0; i < 4; i++) b0[i] = Wq[(size_t)i * nQ];
#pragma unroll
        for (int i = 0; i < 4; i++) b1[i] = Wq[(size_t)(4 + i) * nQ];
#pragma unroll
        for (int k0 = 0; k0 < kc; k0 += 8) {
            // consume b0 (k0..k0+3), refill b0 from k0+8 (no true dep: hoistable)
#pragma unroll
            for (int i = 0; i < 4; i++) fma16(b0[i], xq[k0 + i], a0, a1, a2, a3);
            if (k0 + 8 < kc) {
#pragma unroll
                for (int i = 0; i < 4; i++) b0[i] = Wq[(size_t)(k0 + 8 + i) * nQ];
            }
            // consume b1 (k0+4..k0+7), refill b1 from k0+12
#pragma unroll
            for (int i = 0; i < 4; i++) fma16(b1[i], xq[k0 + 4 + i], a0, a1, a2, a3);
            if (k0 + 12 < kc) {
#pragma unroll
                for (int i = 0; i < 4; i++) b1[i] = Wq[(size_t)(k0 + 12 + i) * nQ];
            }
        }
    } else {
        // small kc (o1 head: kc=12) — plain loop, no big preload (spill-safe)
#pragma unroll 4
        for (int k = 0; k < kc; k++) {
            float4 w = Wq[(size_t)k * nQ];
            fma16(w, xq[k], a0, a1, a2, a3);
        }
    }
    float4* dq = (float4*)dst;
    dq[(g * 4 + 0) * nQ + j] = a0;
    dq[(g * 4 + 1) * nQ + j] = a1;
    dq[(g * 4 + 2) * nQ + j] = a2;
    dq[(g * 4 + 3) * nQ + j] = a3;
}

// ---------------- main kernel ----------------

struct Args {
    const float *params, *disp;
    const float *embed_b, *embed_g, *embed_beta;
    const float *skip_b;
    const float *gates_b;
    const float *inln_g, *inln_b, *hln_g, *hln_b, *sln_g, *sln_b;
    const float *ab1, *aw2, *ab2;
    const float *rb1, *rb2, *rln_g, *rln_b;
    const float *ob1, *oln_g, *oln_b, *ow2, *ob2;
    const float *gw, *a1w, *r1w, *r2w, *ew, *sw, *o1w;
    float* out;
};

__global__ __launch_bounds__(NTH, 1) void xlstm_kernel(Args A) {
    const int tid = threadIdx.x;
    const int blk = blockIdx.x;          // rows 4*blk .. 4*blk+3
    const int n = tid & 255;             // neuron
    const int r = tid >> 8;              // row slot 0..3

    __shared__ __align__(16) float g4[16384];    // 64 KB matvec partials
    __shared__ __align__(16) float bufT[512 * 4]; // xnhn_T / r1out_T  [k][4]
    __shared__ __align__(16) float cT[256 * 4];   // c_prev transposed
    __shared__ __align__(16) float hT[256 * 4];   // h transposed
    __shared__ __align__(16) float yT[384 * 4];   // head input transposed
    __shared__ float skv[4 * 128];                // skip activations [r][m]
    __shared__ __align__(16) float xtT[17 * 4];   // input features [k][r]
    __shared__ float scrA[40], scrB[40];          // reduction scratch (ping-pong)

    // per-(neuron,row) state in registers
    float xr = 0.f;
    float hreg[LL] = {0.f, 0.f, 0.f};
    float creg[LL] = {0.f, 0.f, 0.f};

    int rp = 0;
    auto RED = [&](float a, float b) {
        float2 res = red2row(a, b, (rp & 1) ? scrB : scrA, tid);
        rp++;
        return res;
    };
    auto REDH = [&](float a, float b) {
        float2 res = red2head(a, b, (rp & 1) ? scrB : scrA, tid);
        rp++;
        return res;
    };

    // stage constant params once: xtT[1+k][rr]
    if (tid < 64) {
        int k = tid >> 2, rr = tid & 3;
        xtT[(1 + k) * 4 + rr] = A.params[(4 * blk + rr) * 16 + k];
    }
    __syncthreads();

    for (int t = 0; t < TT; t++) {
        if (tid < 4) xtT[tid] = A.disp[(4 * blk + tid) * TT + t];
        __syncthreads();   // xtT ready; also fences prev-step LDS reuse

        // ---- embed: ev[r][n] ----
        float ev = A.embed_b[n];
#pragma unroll
        for (int k = 0; k < 17; k++) ev = fmaf(A.ew[k * 256 + n], xtT[k * 4 + r], ev);

        // ---- skip (threads 0..511): skv[r2][m] ----
        if (tid < 512) {
            int m = tid & 127, r2 = tid >> 7;
            float s = A.skip_b[m];
#pragma unroll
            for (int k = 0; k < 17; k++) s = fmaf(A.sw[k * 128 + m], xtT[k * 4 + r2], s);
            skv[r2 * 128 + m] = relu(s);
        }

        float2 f2 = RED(ev, ev * ev);
        float mu = f2.x / HH;
        float inv = rsqrtf(f2.y / HH - mu * mu + LN_EPS);
        xr = relu((ev - mu) * inv * A.embed_g[n] + A.embed_beta[n]);

#pragma unroll
        for (int l = 0; l < LL; l++) {
            // ---- xn = LN(x), hn = LN(h); stage bufT (transposed) + cT ----
            f2 = RED(xr, xr * xr);
            mu = f2.x / HH; inv = rsqrtf(f2.y / HH - mu * mu + LN_EPS);
            bufT[n * 4 + r] = (xr - mu) * inv * A.inln_g[l * HH + n] + A.inln_b[l * HH + n];
            float hv = hreg[l];
            f2 = RED(hv, hv * hv);
            mu = f2.x / HH; inv = rsqrtf(f2.y / HH - mu * mu + LN_EPS);
            bufT[(256 + n) * 4 + r] = (hv - mu) * inv * A.hln_g[l * HH + n] + A.hln_b[l * HH + n];
            cT[n * 4 + r] = creg[l];
            __syncthreads();

            // ---- imp = sigmoid(tanh(c @ aw1 + ab1) @ aw2 + ab2) ----
            matvecR<256, 256, 16>(A.a1w + (size_t)l * (256 * 256), cT, g4, tid);
            __syncthreads();
            float s = A.ab1[l * HH + n];
#pragma unroll
            for (int g = 0; g < 16; g++) s += g4[(g * 4 + r) * 256 + n];
            float v = fast_tanh(s) * A.aw2[l * HH + n];
            f2 = RED(v, 0.f);                       // barrier frees g4 for gates
            float impv = fast_sigmoid(f2.x + A.ab2[l]);

            // ---- gates = [xn,hn] @ gates_w ----
            matvecR<512, 1024, 4>(A.gw + (size_t)l * (512 * 1024), bufT, g4, tid);
            __syncthreads();
            const float* gb = A.gates_b + l * 1024;
            float si = gb[n], sf = gb[256 + n], sg = gb[512 + n], so = gb[768 + n];
#pragma unroll
            for (int g = 0; g < 4; g++) {
                si += g4[(g * 4 + r) * 1024 + n];
                sf += g4[(g * 4 + r) * 1024 + 256 + n];
                sg += g4[(g * 4 + r) * 1024 + 512 + n];
                so += g4[(g * 4 + r) * 1024 + 768 + n];
            }
            float og = fast_sigmoid(so);
            v = (fast_sigmoid(sf) * creg[l] + fast_sigmoid(si) * fast_tanh(sg)) * impv;
            f2 = RED(v, v * v);
            mu = f2.x / HH; inv = rsqrtf(f2.y / HH - mu * mu + LN_EPS);
            float cn = (v - mu) * inv * A.sln_g[l * HH + n] + A.sln_b[l * HH + n];
            creg[l] = cn;
            float hn = og * fast_tanh(cn);
            hreg[l] = hn;
            hT[n * 4 + r] = hn;
            __syncthreads();

            // ---- residual MLP ----
            matvecR<256, 512, 8>(A.r1w + (size_t)l * (256 * 512), hT, g4, tid);
            __syncthreads();
            {
                int m = tid & 511, rr = tid >> 9;    // rows rr and rr+2
#pragma unroll
                for (int p = 0; p < 2; p++) {
                    int r2 = rr + 2 * p;
                    float ss = A.rb1[l * 512 + m];
#pragma unroll
                    for (int g = 0; g < 8; g++) ss += g4[(g * 4 + r2) * 512 + m];
                    bufT[m * 4 + r2] = relu(ss);
                }
            }
            __syncthreads();

            matvecR<512, 256, 16>(A.r2w + (size_t)l * (512 * 256), bufT, g4, tid);
            __syncthreads();
            s = A.rb2[l * HH + n] + hreg[l];
#pragma unroll
            for (int g = 0; g < 16; g++) s += g4[(g * 4 + r) * 256 + n];
            f2 = RED(s, s * s);
            mu = f2.x / HH; inv = rsqrtf(f2.y / HH - mu * mu + LN_EPS);
            xr = (s - mu) * inv * A.rln_g[l * HH + n] + A.rln_b[l * HH + n] + xr;
        }

        // ---- output head ----
        yT[n * 4 + r] = xr;
        if (n < 128) yT[(256 + n) * 4 + r] = skv[r * 128 + n];
        __syncthreads();
        matvecR<384, 128, 32>(A.o1w, yT, g4, tid);   // kc=12 -> plain-loop path
        __syncthreads();
        float hs = 0.f;
        if (tid < 512) {
            int m = tid & 127, r2 = tid >> 7;
            hs = A.ob1[m];
#pragma unroll
            for (int g = 0; g < 32; g++) hs += g4[(g * 4 + r2) * 128 + m];
        }
        float2 f2o = REDH(hs, hs * hs);
        float muo = f2o.x / 128.f;
        float invo = rsqrtf(f2o.y / 128.f - muo * muo + LN_EPS);
        float contrib = 0.f;
        if (tid < 512) {
            int m = tid & 127;
            contrib = relu((hs - muo) * invo * A.oln_g[m] + A.oln_b[m]) * A.ow2[m];
        }
        f2o = REDH(contrib, 0.f);
        if (tid < 512 && (tid & 127) == 0) {
            int r2 = tid >> 7;
            A.out[(4 * blk + r2) * TT + t] = f2o.x + A.ob2[0];
        }
        __syncthreads();   // protect xtT / g4 / yT for next step
    }
}

// ---------------- launch ----------------

extern "C" void kernel_launch(void* const* d_in, const int* in_sizes, int n_in,
                              void* d_out, int out_size, void* d_ws, size_t ws_size,
                              hipStream_t stream) {
    Args A;
    A.params     = (const float*)d_in[0];
    A.disp       = (const float*)d_in[1];
    A.ew         = (const float*)d_in[2];
    A.embed_b    = (const float*)d_in[3];
    A.embed_g    = (const float*)d_in[4];
    A.embed_beta = (const float*)d_in[5];
    A.sw         = (const float*)d_in[6];
    A.skip_b     = (const float*)d_in[7];
    A.gw         = (const float*)d_in[8];
    A.gates_b    = (const float*)d_in[9];
    A.inln_g     = (const float*)d_in[10];
    A.inln_b     = (const float*)d_in[11];
    A.hln_g      = (const float*)d_in[12];
    A.hln_b      = (const float*)d_in[13];
    A.sln_g      = (const float*)d_in[14];
    A.sln_b      = (const float*)d_in[15];
    A.a1w        = (const float*)d_in[16];
    A.ab1        = (const float*)d_in[17];
    A.aw2        = (const float*)d_in[18];
    A.ab2        = (const float*)d_in[19];
    A.r1w        = (const float*)d_in[20];
    A.rb1        = (const float*)d_in[21];
    A.r2w        = (const float*)d_in[22];
    A.rb2        = (const float*)d_in[23];
    A.rln_g      = (const float*)d_in[24];
    A.rln_b      = (const float*)d_in[25];
    A.o1w        = (const float*)d_in[26];
    A.ob1        = (const float*)d_in[27];
    A.oln_g      = (const float*)d_in[28];
    A.oln_b      = (const float*)d_in[29];
    A.ow2        = (const float*)d_in[30];
    A.ob2        = (const float*)d_in[31];
    A.out        = (float*)d_out;

    xlstm_kernel<<<32, NTH, 0, stream>>>(A);
}

// Round 8
// 34928.232 us; speedup vs baseline: 3.7009x; 3.7009x over previous
//
#include <hip/hip_runtime.h>
#include <cstdint>

#define TT 256
#define HH 256
#define LL 3
#define NTH 512
#define SWG 8          // WGs per cluster
#define CLN 32         // clusters
#define RW 4           // rows per cluster
#define LN_EPS 1e-5f
#define ACTSTRIDE 8192 // floats per cluster in d_ws activity region

// ---------------- helpers ----------------

__device__ __forceinline__ float fast_sigmoid(float x) {
    return 1.f / (1.f + __expf(-x));
}
__device__ __forceinline__ float fast_tanh(float x) {
    float xc = fminf(fmaxf(x, -15.f), 15.f);
    float e = __expf(2.f * xc);
    return 1.f - 2.f / (e + 1.f);
}
__device__ __forceinline__ float relu(float x) { return fmaxf(x, 0.f); }

// Dual-row (sum, sumsq) reduction. Thread (n=tid&255, p=tid>>8) owns rows
// p and p+2. Waves 0-3 carry p=0 (rows 0,2), waves 4-7 carry p=1 (rows 1,3).
// Returns (sumA, sqA, sumB, sqB) for this thread's rows. scr: 32 floats.
__device__ __forceinline__ float4 rowsum4(float s0, float q0, float s1, float q1,
                                          float* scr, int tid) {
#pragma unroll
    for (int o = 32; o > 0; o >>= 1) {
        s0 += __shfl_down(s0, o); q0 += __shfl_down(q0, o);
        s1 += __shfl_down(s1, o); q1 += __shfl_down(q1, o);
    }
    int w = tid >> 6;
    if ((tid & 63) == 0) { scr[w*4] = s0; scr[w*4+1] = q0; scr[w*4+2] = s1; scr[w*4+3] = q1; }
    __syncthreads();
    int base = (tid >> 8) * 16;
    float sA = 0, qA = 0, sB = 0, qB = 0;
#pragma unroll
    for (int i = 0; i < 4; i++) {
        sA += scr[base + i*4];     qA += scr[base + i*4 + 1];
        sB += scr[base + i*4 + 2]; qB += scr[base + i*4 + 3];
    }
    __syncthreads();
    return make_float4(sA, qA, sB, qB);
}

// Head reduction: thread (mm=tid&127, row=tid>>7); row r spans waves 2r,2r+1.
__device__ __forceinline__ float2 red2head(float a, float b, float* scr, int tid) {
#pragma unroll
    for (int o = 32; o > 0; o >>= 1) {
        a += __shfl_down(a, o);
        b += __shfl_down(b, o);
    }
    int w = tid >> 6;
    if ((tid & 63) == 0) { scr[w] = a; scr[8 + w] = b; }
    __syncthreads();
    int r = tid >> 7;
    float2 out = make_float2(scr[2*r] + scr[2*r+1], scr[8+2*r] + scr[8+2*r+1]);
    __syncthreads();
    return out;
}

__device__ __forceinline__ void fma16(float4 w, float4 x,
                                      float4& a0, float4& a1, float4& a2, float4& a3) {
    a0.x = fmaf(w.x, x.x, a0.x); a0.y = fmaf(w.y, x.x, a0.y);
    a0.z = fmaf(w.z, x.x, a0.z); a0.w = fmaf(w.w, x.x, a0.w);
    a1.x = fmaf(w.x, x.y, a1.x); a1.y = fmaf(w.y, x.y, a1.y);
    a1.z = fmaf(w.z, x.y, a1.z); a1.w = fmaf(w.w, x.y, a1.w);
    a2.x = fmaf(w.x, x.z, a2.x); a2.y = fmaf(w.y, x.z, a2.y);
    a2.z = fmaf(w.z, x.z, a2.z); a2.w = fmaf(w.w, x.z, a2.w);
    a3.x = fmaf(w.x, x.w, a3.x); a3.y = fmaf(w.y, x.w, a3.y);
    a3.z = fmaf(w.z, x.w, a3.z); a3.w = fmaf(w.w, x.w, a3.w);
}

// ---------------- main kernel ----------------

struct Args {
    const float *params, *disp;
    const float *embed_b, *embed_g, *embed_beta;
    const float *skip_b;
    const float *gates_b;
    const float *inln_g, *inln_b, *hln_g, *hln_b, *sln_g, *sln_b;
    const float *ab1, *aw2, *ab2;
    const float *rb1, *rb2, *rln_g, *rln_b;
    const float *ob1, *oln_g, *oln_b, *ow2, *ob2;
    const float *gw, *a1w, *r1w, *r2w, *ew, *sw, *o1w;
    float* out;
    float* act;   // cluster activation buffers
    int* bar;     // cluster barrier counters (64-int stride per cluster)
};

__global__ __launch_bounds__(NTH) void xlstm_kernel(Args A) {
    const int tid = threadIdx.x;
    const int cid = blockIdx.x & 31;   // cluster: members at blockIdx%32==cid
    const int m   = blockIdx.x >> 5;   // member 0..7 (same XCD under %8 heuristic)
    const int n   = tid & 255;
    const int p   = tid >> 8;          // 0/1 -> rows p, p+2
    const int rA = p, rB = p + 2;

    float* gatesB = A.act + (size_t)cid * ACTSTRIDE;   // [4][1024]
    float* r1B = gatesB + 4096;                        // [4][512]
    float* r2B = gatesB + 6144;                        // [4][256]
    float* a1B = gatesB + 7168;                        // [8][4] imp partials
    float* o1B = gatesB + 7232;                        // [4][128]
    int* bar = A.bar + cid * 64;

    __shared__ __align__(16) float4 P4[2304];     // matvec partials (36.9 KB)
    __shared__ __align__(16) float4 xnhnT[512];   // LN'd [xn,hn], [k] x rows
    __shared__ __align__(16) float4 cT4[256];
    __shared__ __align__(16) float4 hT4[256];
    __shared__ __align__(16) float4 xT4[256];
    __shared__ __align__(16) float4 skT4[128];
    __shared__ __align__(16) float4 r1T4[512];
    __shared__ float xtT[17 * 4];
    __shared__ float scr[64];

    // replicated per-thread state (identical in all 8 member WGs)
    float x2[2] = {0.f, 0.f};
    float h2[LL][2] = {{0.f,0.f},{0.f,0.f},{0.f,0.f}};
    float c2[LL][2] = {{0.f,0.f},{0.f,0.f},{0.f,0.f}};

    int ep = 0;
    auto cbar = [&]() {
        ep++;
        __syncthreads();
        if (tid == 0) {
            __hip_atomic_fetch_add(bar, 1, __ATOMIC_RELEASE, __HIP_MEMORY_SCOPE_AGENT);
            while (__hip_atomic_load(bar, __ATOMIC_ACQUIRE, __HIP_MEMORY_SCOPE_AGENT) < SWG * ep)
                __builtin_amdgcn_s_sleep(2);
        }
        __syncthreads();
    };

    if (tid < 64) {
        int k = tid >> 2, rr = tid & 3;
        xtT[(1 + k) * 4 + rr] = A.params[(RW * cid + rr) * 16 + k];
    }
    __syncthreads();

    for (int t = 0; t < TT; t++) {
        if (tid < 4) xtT[tid] = A.disp[(RW * cid + tid) * TT + t];
        __syncthreads();

        // ---- embed + skip (redundant in every member WG) ----
        float e0 = A.embed_b[n], e1 = e0;
#pragma unroll 4
        for (int k = 0; k < 17; k++) {
            float w = A.ew[k * 256 + n];
            e0 = fmaf(w, xtT[k * 4 + rA], e0);
            e1 = fmaf(w, xtT[k * 4 + rB], e1);
        }
        {
            int mm = tid & 127, q = tid >> 7;
            float s = A.skip_b[mm];
#pragma unroll 4
            for (int k = 0; k < 17; k++) s = fmaf(A.sw[k * 128 + mm], xtT[k * 4 + q], s);
            ((float*)&skT4[mm])[q] = relu(s);
        }
        float4 rs = rowsum4(e0, e0 * e0, e1, e1 * e1, scr, tid);
        {
            float mu = rs.x * (1.f/HH), inv = rsqrtf(rs.y * (1.f/HH) - mu*mu + LN_EPS);
            x2[0] = relu((e0 - mu) * inv * A.embed_g[n] + A.embed_beta[n]);
            mu = rs.z * (1.f/HH); inv = rsqrtf(rs.w * (1.f/HH) - mu*mu + LN_EPS);
            x2[1] = relu((e1 - mu) * inv * A.embed_g[n] + A.embed_beta[n]);
        }

#pragma unroll 1
        for (int l = 0; l < LL; l++) {
            // ---- phase A (redundant): xn, hn, stage cT ----
            rs = rowsum4(x2[0], x2[0]*x2[0], x2[1], x2[1]*x2[1], scr, tid);
            {
                const float* g = A.inln_g + l*HH; const float* b = A.inln_b + l*HH;
                float mu = rs.x*(1.f/HH), inv = rsqrtf(rs.y*(1.f/HH) - mu*mu + LN_EPS);
                ((float*)&xnhnT[n])[rA] = (x2[0] - mu) * inv * g[n] + b[n];
                mu = rs.z*(1.f/HH); inv = rsqrtf(rs.w*(1.f/HH) - mu*mu + LN_EPS);
                ((float*)&xnhnT[n])[rB] = (x2[1] - mu) * inv * g[n] + b[n];
            }
            float hA = h2[l][0], hB = h2[l][1];
            rs = rowsum4(hA, hA*hA, hB, hB*hB, scr, tid);
            {
                const float* g = A.hln_g + l*HH; const float* b = A.hln_b + l*HH;
                float mu = rs.x*(1.f/HH), inv = rsqrtf(rs.y*(1.f/HH) - mu*mu + LN_EPS);
                ((float*)&xnhnT[256 + n])[rA] = (hA - mu) * inv * g[n] + b[n];
                mu = rs.z*(1.f/HH); inv = rsqrtf(rs.w*(1.f/HH) - mu*mu + LN_EPS);
                ((float*)&xnhnT[256 + n])[rB] = (hB - mu) * inv * g[n] + b[n];
            }
            ((float*)&cT4[n])[rA] = c2[l][0];
            ((float*)&cT4[n])[rB] = c2[l][1];
            __syncthreads();

            // ---- MV1: gates slice (K=512, our 128 cols) ----
            {
                int j = tid & 31, kg = tid >> 5;            // 16 k-groups x 32
                const float4* Wq = (const float4*)A.gw + (size_t)l*512*256 + (m*32 + j);
                float4 a0={0,0,0,0}, a1v={0,0,0,0}, a2={0,0,0,0}, a3={0,0,0,0};
                int k0 = kg * 32;
#pragma unroll 8
                for (int kk = 0; kk < 32; kk++) {
                    int k = k0 + kk;
                    float4 w = Wq[(size_t)k * 256];
                    fma16(w, xnhnT[k], a0, a1v, a2, a3);
                }
                int b = kg*129 + j*4;
                P4[b] = a0; P4[b+1] = a1v; P4[b+2] = a2; P4[b+3] = a3;
            }
            __syncthreads();
            if (tid < 128) {
                int j2 = tid >> 2, row = tid & 3;
                float4 s = {0,0,0,0};
#pragma unroll
                for (int kg = 0; kg < 16; kg++) {
                    float4 v = P4[kg*129 + j2*4 + row];
                    s.x += v.x; s.y += v.y; s.z += v.z; s.w += v.w;
                }
                ((float4*)(gatesB + row*1024 + m*128))[j2] = s;
            }
            __syncthreads();
            // ---- MV1b: a1 slice (K=256, our 32 cols) + imp partial ----
            if (tid < 256) {
                int j = tid & 7, kg = tid >> 3;             // 32 k-groups x 8
                const float4* Wq = (const float4*)A.a1w + (size_t)l*256*64 + (m*8 + j);
                float4 a0={0,0,0,0}, a1v={0,0,0,0}, a2={0,0,0,0}, a3={0,0,0,0};
                int k0 = kg * 8;
#pragma unroll
                for (int kk = 0; kk < 8; kk++) {
                    int k = k0 + kk;
                    float4 w = Wq[(size_t)k * 64];
                    fma16(w, cT4[k], a0, a1v, a2, a3);
                }
                int b = kg*33 + j*4;
                P4[b] = a0; P4[b+1] = a1v; P4[b+2] = a2; P4[b+3] = a3;
            }
            __syncthreads();
            if (tid < 32) {
                int j2 = tid >> 2, row = tid & 3;
                float4 s = {0,0,0,0};
#pragma unroll
                for (int kg = 0; kg < 32; kg++) {
                    float4 v = P4[kg*33 + j2*4 + row];
                    s.x += v.x; s.y += v.y; s.z += v.z; s.w += v.w;
                }
                const float* ab1p = A.ab1 + l*HH + m*32 + j2*4;
                const float* aw2p = A.aw2 + l*HH + m*32 + j2*4;
                float d = fast_tanh(s.x + ab1p[0]) * aw2p[0]
                        + fast_tanh(s.y + ab1p[1]) * aw2p[1]
                        + fast_tanh(s.z + ab1p[2]) * aw2p[2]
                        + fast_tanh(s.w + ab1p[3]) * aw2p[3];
                scr[tid] = d;
            }
            __syncthreads();
            if (tid < 4) {
                float s = 0.f;
#pragma unroll
                for (int j2 = 0; j2 < 8; j2++) s += scr[j2*4 + tid];
                a1B[m*4 + tid] = s;
            }
            cbar();   // B1: gates + a1 partials visible

            // ---- phase B (redundant): imp, c, h ----
            float imp0, imp1;
            {
                float sA = A.ab2[l], sB = A.ab2[l];
#pragma unroll
                for (int mm = 0; mm < SWG; mm++) { sA += a1B[mm*4 + rA]; sB += a1B[mm*4 + rB]; }
                imp0 = fast_sigmoid(sA); imp1 = fast_sigmoid(sB);
            }
            const float* gb = A.gates_b + l*1024;
            float craw0, craw1, og0, og1;
            {
                const float* go = gatesB + rA*1024;
                float ii = fast_sigmoid(go[n] + gb[n]);
                float ff = fast_sigmoid(go[256+n] + gb[256+n]);
                float gg = fast_tanh(go[512+n] + gb[512+n]);
                og0 = fast_sigmoid(go[768+n] + gb[768+n]);
                craw0 = (ff * c2[l][0] + ii * gg) * imp0;
            }
            {
                const float* go = gatesB + rB*1024;
                float ii = fast_sigmoid(go[n] + gb[n]);
                float ff = fast_sigmoid(go[256+n] + gb[256+n]);
                float gg = fast_tanh(go[512+n] + gb[512+n]);
                og1 = fast_sigmoid(go[768+n] + gb[768+n]);
                craw1 = (ff * c2[l][1] + ii * gg) * imp1;
            }
            rs = rowsum4(craw0, craw0*craw0, craw1, craw1*craw1, scr, tid);
            {
                const float* g = A.sln_g + l*HH; const float* b = A.sln_b + l*HH;
                float mu = rs.x*(1.f/HH), inv = rsqrtf(rs.y*(1.f/HH) - mu*mu + LN_EPS);
                float cn = (craw0 - mu) * inv * g[n] + b[n];
                c2[l][0] = cn; float hh = og0 * fast_tanh(cn);
                h2[l][0] = hh; ((float*)&hT4[n])[rA] = hh;
                mu = rs.z*(1.f/HH); inv = rsqrtf(rs.w*(1.f/HH) - mu*mu + LN_EPS);
                cn = (craw1 - mu) * inv * g[n] + b[n];
                c2[l][1] = cn; hh = og1 * fast_tanh(cn);
                h2[l][1] = hh; ((float*)&hT4[n])[rB] = hh;
            }
            __syncthreads();

            // ---- MV2: r1 slice (K=256, our 64 cols), relu inline ----
            {
                int j = tid & 15, kg = tid >> 4;            // 32 k-groups x 16
                const float4* Wq = (const float4*)A.r1w + (size_t)l*256*128 + (m*16 + j);
                float4 a0={0,0,0,0}, a1v={0,0,0,0}, a2={0,0,0,0}, a3={0,0,0,0};
                int k0 = kg * 8;
#pragma unroll
                for (int kk = 0; kk < 8; kk++) {
                    int k = k0 + kk;
                    float4 w = Wq[(size_t)k * 128];
                    fma16(w, hT4[k], a0, a1v, a2, a3);
                }
                int b = kg*65 + j*4;
                P4[b] = a0; P4[b+1] = a1v; P4[b+2] = a2; P4[b+3] = a3;
            }
            __syncthreads();
            if (tid < 64) {
                int j2 = tid >> 2, row = tid & 3;
                float4 s = {0,0,0,0};
#pragma unroll
                for (int kg = 0; kg < 32; kg++) {
                    float4 v = P4[kg*65 + j2*4 + row];
                    s.x += v.x; s.y += v.y; s.z += v.z; s.w += v.w;
                }
                const float* rb1p = A.rb1 + l*512 + m*64 + j2*4;
                s.x = relu(s.x + rb1p[0]); s.y = relu(s.y + rb1p[1]);
                s.z = relu(s.z + rb1p[2]); s.w = relu(s.w + rb1p[3]);
                ((float4*)(r1B + row*512 + m*64))[j2] = s;
            }
            cbar();   // B2: r1 visible

            // ---- MV3: r2 slice (K=512, our 32 cols) ----
            for (int idx = tid; idx < 2048; idx += NTH) {
                int row = idx >> 9, k = idx & 511;
                ((float*)&r1T4[k])[row] = r1B[row*512 + k];
            }
            __syncthreads();
            {
                int j = tid & 7, kg = tid >> 3;             // 64 k-groups x 8
                const float4* Wq = (const float4*)A.r2w + (size_t)l*512*64 + (m*8 + j);
                float4 a0={0,0,0,0}, a1v={0,0,0,0}, a2={0,0,0,0}, a3={0,0,0,0};
                int k0 = kg * 8;
#pragma unroll
                for (int kk = 0; kk < 8; kk++) {
                    int k = k0 + kk;
                    float4 w = Wq[(size_t)k * 64];
                    fma16(w, r1T4[k], a0, a1v, a2, a3);
                }
                int b = kg*33 + j*4;
                P4[b] = a0; P4[b+1] = a1v; P4[b+2] = a2; P4[b+3] = a3;
            }
            __syncthreads();
            if (tid < 32) {
                int j2 = tid >> 2, row = tid & 3;
                float4 s = {0,0,0,0};
#pragma unroll
                for (int kg = 0; kg < 64; kg++) {
                    float4 v = P4[kg*33 + j2*4 + row];
                    s.x += v.x; s.y += v.y; s.z += v.z; s.w += v.w;
                }
                ((float4*)(r2B + row*256 + m*32))[j2] = s;
            }
            cbar();   // B3: r2 visible

            // ---- phase C (redundant): x = LN(r2 + h) + residual ----
            const float* rb2p = A.rb2 + l*HH;
            float s0 = r2B[rA*256 + n] + rb2p[n] + h2[l][0];
            float s1 = r2B[rB*256 + n] + rb2p[n] + h2[l][1];
            rs = rowsum4(s0, s0*s0, s1, s1*s1, scr, tid);
            {
                const float* g = A.rln_g + l*HH; const float* b = A.rln_b + l*HH;
                float mu = rs.x*(1.f/HH), inv = rsqrtf(rs.y*(1.f/HH) - mu*mu + LN_EPS);
                x2[0] = (s0 - mu) * inv * g[n] + b[n] + x2[0];
                mu = rs.z*(1.f/HH); inv = rsqrtf(rs.w*(1.f/HH) - mu*mu + LN_EPS);
                x2[1] = (s1 - mu) * inv * g[n] + b[n] + x2[1];
            }
        }   // layers

        // ---- head: o1 slice (K=384, our 16 cols) ----
        ((float*)&xT4[n])[rA] = x2[0];
        ((float*)&xT4[n])[rB] = x2[1];
        __syncthreads();
        {
            int j = tid & 3, kg = tid >> 2;                 // 128 k-groups x 4
            const float4* Wq = (const float4*)A.o1w + (m*4 + j);
            float4 a0={0,0,0,0}, a1v={0,0,0,0}, a2={0,0,0,0}, a3={0,0,0,0};
            int k0 = kg * 3;
#pragma unroll
            for (int kk = 0; kk < 3; kk++) {
                int k = k0 + kk;
                float4 w = Wq[(size_t)k * 32];
                float4 x = (k < 256) ? xT4[k] : skT4[k - 256];
                fma16(w, x, a0, a1v, a2, a3);
            }
            int b = kg*17 + j*4;
            P4[b] = a0; P4[b+1] = a1v; P4[b+2] = a2; P4[b+3] = a3;
        }
        __syncthreads();
        if (tid < 16) {
            int j2 = tid >> 2, row = tid & 3;
            float4 s = {0,0,0,0};
#pragma unroll
            for (int kg = 0; kg < 128; kg++) {
                float4 v = P4[kg*17 + j2*4 + row];
                s.x += v.x; s.y += v.y; s.z += v.z; s.w += v.w;
            }
            ((float4*)(o1B + row*128 + m*16))[j2] = s;
        }
        cbar();   // B10: o1 visible

        if (m == 0) {
            int mm = tid & 127, row = tid >> 7;
            float v = o1B[row*128 + mm] + A.ob1[mm];
            float2 f2 = red2head(v, v * v, scr, tid);
            float mu = f2.x * (1.f/128.f);
            float inv = rsqrtf(f2.y * (1.f/128.f) - mu*mu + LN_EPS);
            float contrib = relu((v - mu) * inv * A.oln_g[mm] + A.oln_b[mm]) * A.ow2[mm];
            f2 = red2head(contrib, 0.f, scr, tid);
            if (mm == 0) A.out[(RW*cid + row) * TT + t] = f2.x + A.ob2[0];
        }
        __syncthreads();   // protect xtT / LDS for next step
    }
}

// ---------------- launch ----------------

extern "C" void kernel_launch(void* const* d_in, const int* in_sizes, int n_in,
                              void* d_out, int out_size, void* d_ws, size_t ws_size,
                              hipStream_t stream) {
    // zero cluster barrier counters (32 clusters x 64 ints)
    hipMemsetAsync(d_ws, 0, CLN * 64 * sizeof(int), stream);

    Args A;
    A.params     = (const float*)d_in[0];
    A.disp       = (const float*)d_in[1];
    A.ew         = (const float*)d_in[2];
    A.embed_b    = (const float*)d_in[3];
    A.embed_g    = (const float*)d_in[4];
    A.embed_beta = (const float*)d_in[5];
    A.sw         = (const float*)d_in[6];
    A.skip_b     = (const float*)d_in[7];
    A.gw         = (const float*)d_in[8];
    A.gates_b    = (const float*)d_in[9];
    A.inln_g     = (const float*)d_in[10];
    A.inln_b     = (const float*)d_in[11];
    A.hln_g      = (const float*)d_in[12];
    A.hln_b      = (const float*)d_in[13];
    A.sln_g      = (const float*)d_in[14];
    A.sln_b      = (const float*)d_in[15];
    A.a1w        = (const float*)d_in[16];
    A.ab1        = (const float*)d_in[17];
    A.aw2        = (const float*)d_in[18];
    A.ab2        = (const float*)d_in[19];
    A.r1w        = (const float*)d_in[20];
    A.rb1        = (const float*)d_in[21];
    A.r2w        = (const float*)d_in[22];
    A.rb2        = (const float*)d_in[23];
    A.rln_g      = (const float*)d_in[24];
    A.rln_b      = (const float*)d_in[25];
    A.o1w        = (const float*)d_in[26];
    A.ob1        = (const float*)d_in[27];
    A.oln_g      = (const float*)d_in[28];
    A.oln_b      = (const float*)d_in[29];
    A.ow2        = (const float*)d_in[30];
    A.ob2        = (const float*)d_in[31];
    A.out        = (float*)d_out;
    A.bar        = (int*)d_ws;
    A.act        = (float*)d_ws + 2048;   // after 8KB barrier region

    xlstm_kernel<<<CLN * SWG, NTH, 0, stream>>>(A);
}